// Round 5
// baseline (163.306 us; speedup 1.0000x reference)
//
#include <hip/hip_runtime.h>
#include <cstdint>
#include <cstddef>

typedef short bf16x8 __attribute__((ext_vector_type(8)));
typedef float f32x4 __attribute__((ext_vector_type(4)));

#define DM 1024
#define NHEADS 16
#define NGROUPS 4
#define DK 64
#define BATCH 2
#define SEQ 2048
#define MROWS 4096

#define QB_ELEMS   ((size_t)BATCH*NHEADS*SEQ*DK)   // 4M shorts
#define KB_ELEMS   ((size_t)BATCH*NGROUPS*SEQ*DK)  // 1M
#define VT_ELEMS   KB_ELEMS                        // 1M  ([b][g][d][col] permuted)
#define XC_ELEMS   ((size_t)MROWS*DM)              // 4M  (xbf, later reused as ctx)
#define WQKV_ELEMS ((size_t)1536*DM)
#define WO_ELEMS   ((size_t)DM*DM)

#define SCL_Q 0.180336880f    // (1/sqrt(64)) * log2(e), folded into Q

__device__ __forceinline__ ushort f2bf(float f) {          // RNE
    union { float f; uint32_t u; } a; a.f = f;
    uint32_t u = a.u;
    return (ushort)((u + 0x7FFFu + ((u >> 16) & 1u)) >> 16);
}

// async global->LDS, 16B/lane; LDS dest = wave-uniform base + lane*16
__device__ __forceinline__ void gll16(const void* g, void* l) {
    __builtin_amdgcn_global_load_lds((const __attribute__((address_space(1))) void*)g,
                                     (__attribute__((address_space(3))) void*)l, 16, 0, 0);
}

// ---------------------------------------------------------------------------
// Prep: tiled transposes of W_Q/W_O/W_K/W_V -> bf16 k-contiguous rows,
// x fp32->bf16 convert, bias concat.
// ---------------------------------------------------------------------------
__global__ __launch_bounds__(256) void gqa_prep_kernel(
        const float* __restrict__ x,
        const float* __restrict__ WQ, const float* __restrict__ WK,
        const float* __restrict__ WV, const float* __restrict__ WO,
        const float* __restrict__ bQ, const float* __restrict__ bK,
        const float* __restrict__ bV,
        ushort* __restrict__ xbf, ushort* __restrict__ WqkvT,
        ushort* __restrict__ WoT, float* __restrict__ bcat)
{
    __shared__ float tl[64][65];
    const int bid = blockIdx.x, tid = threadIdx.x;
    if (bid < 640) {
        const float* src; ushort* dst; int src_ld; int r0, c0;
        if (bid < 256) {
            src = WQ; src_ld = 1024; dst = WqkvT;
            r0 = (bid >> 4) * 64; c0 = (bid & 15) * 64;
        } else if (bid < 512) {
            int t = bid - 256;
            src = WO; src_ld = 1024; dst = WoT;
            r0 = (t >> 4) * 64; c0 = (t & 15) * 64;
        } else if (bid < 576) {
            int t = bid - 512; int g = t >> 4;
            src = WK + (size_t)g * 1024 * 64; src_ld = 64;
            dst = WqkvT + (size_t)(1024 + g * 64) * 1024;
            r0 = (t & 15) * 64; c0 = 0;
        } else {
            int t = bid - 576; int g = t >> 4;
            src = WV + (size_t)g * 1024 * 64; src_ld = 64;
            dst = WqkvT + (size_t)(1280 + g * 64) * 1024;
            r0 = (t & 15) * 64; c0 = 0;
        }
        const int rr = tid >> 4, cc = (tid & 15) * 4;
#pragma unroll
        for (int p = 0; p < 4; p++) {
            int r = rr + p * 16;
            float4 v = *(const float4*)(src + (size_t)(r0 + r) * src_ld + c0 + cc);
            tl[cc + 0][r] = v.x; tl[cc + 1][r] = v.y;
            tl[cc + 2][r] = v.z; tl[cc + 3][r] = v.w;
        }
        __syncthreads();
#pragma unroll
        for (int p = 0; p < 4; p++) {
            int c = rr + p * 16;
            ushort4 o;
            o.x = f2bf(tl[c][cc + 0]); o.y = f2bf(tl[c][cc + 1]);
            o.z = f2bf(tl[c][cc + 2]); o.w = f2bf(tl[c][cc + 3]);
            *(ushort4*)(dst + (size_t)(c0 + c) * 1024 + r0 + cc) = o;
        }
    } else if (bid < 896) {
        int cid = bid - 640;
        const float* xs = x + (size_t)cid * 16384;
        ushort* xd = xbf + (size_t)cid * 16384;
#pragma unroll
        for (int p = 0; p < 16; p++) {
            float4 v = *(const float4*)(xs + p * 1024 + tid * 4);
            ushort4 o = { f2bf(v.x), f2bf(v.y), f2bf(v.z), f2bf(v.w) };
            *(ushort4*)(xd + p * 1024 + tid * 4) = o;
        }
    } else {
        for (int i = tid; i < 1536; i += 256) {
            float v = (i < 1024) ? bQ[i] : (i < 1280 ? bK[i - 1024] : bV[i - 1280]);
            bcat[i] = v;
        }
    }
}

// ---------------------------------------------------------------------------
// GEMM: C[4096][N] = A[4096][1024]*B (+bias), BT[N][1024] bf16.
// Tile 128x64, BK=64, 4 waves 2x2 (wave 64x32), gll16 dbuf, 1 barrier/iter.
// Flat grid with XCD-locality swizzle: xcd = i&7 owns bm panels
// {xcd, xcd+8, xcd+16, xcd+24} -> A panel stays in that XCD's L2.
// ---------------------------------------------------------------------------
template<bool QKV_EPI, int BN>
__global__ __launch_bounds__(256, 3) void gqa_gemm_kernel(
        const ushort* __restrict__ A, const ushort* __restrict__ BT,
        const float* __restrict__ bias, float* __restrict__ outF,
        ushort* __restrict__ Qb, ushort* __restrict__ Kb, ushort* __restrict__ Vtg)
{
    __shared__ ushort As[2][128 * 64];   // 16 KB / buf
    __shared__ ushort Bs[2][64 * 64];    //  8 KB / buf
    const int tid = threadIdx.x;
    const int i = blockIdx.x;
    const int xcd = i & 7, slot = i >> 3;
    const int bm = (slot / BN) * 8 + xcd;
    const int bn = slot % BN;
    const int wave = tid >> 6, lane = tid & 63;
    const int wm = (wave & 1) * 64, wn = (wave >> 1) * 32;
    const int lr = lane & 15, lq = lane >> 4;
    const int swz = lr & 7;

    const ushort* srcA[4]; int dstA[4];
    const ushort* srcB[2]; int dstB[2];
#pragma unroll
    for (int p = 0; p < 4; p++) {
        int slt = p * 256 + tid;
        int row = slt >> 3, cb = (slt & 7) ^ (row & 7);
        srcA[p] = A + (size_t)(bm * 128 + row) * 1024 + cb * 8;
        dstA[p] = p * 2048 + wave * 512;
    }
#pragma unroll
    for (int p = 0; p < 2; p++) {
        int slt = p * 256 + tid;
        int row = slt >> 3, cb = (slt & 7) ^ (row & 7);
        srcB[p] = BT + (size_t)(bn * 64 + row) * 1024 + cb * 8;
        dstB[p] = p * 2048 + wave * 512;
    }

    f32x4 acc[4][2];
#pragma unroll
    for (int ii = 0; ii < 4; ii++)
#pragma unroll
        for (int j = 0; j < 2; j++) acc[ii][j] = (f32x4){0.f, 0.f, 0.f, 0.f};

#pragma unroll
    for (int p = 0; p < 4; p++) gll16(srcA[p], &As[0][dstA[p]]);
#pragma unroll
    for (int p = 0; p < 2; p++) gll16(srcB[p], &Bs[0][dstB[p]]);

    for (int kt = 0; kt < 16; kt++) {
        __syncthreads();
        if (kt < 15) {
            int buf = (kt + 1) & 1, ko = (kt + 1) * 64;
#pragma unroll
            for (int p = 0; p < 4; p++) gll16(srcA[p] + ko, &As[buf][dstA[p]]);
#pragma unroll
            for (int p = 0; p < 2; p++) gll16(srcB[p] + ko, &Bs[buf][dstB[p]]);
        }
        const ushort* as = As[kt & 1];
        const ushort* bs = Bs[kt & 1];
        bf16x8 af[2][4], bfr[2][2];
#pragma unroll
        for (int kh = 0; kh < 2; kh++) {
#pragma unroll
            for (int ii = 0; ii < 4; ii++)
                af[kh][ii] = *(const bf16x8*)&as[(wm + ii * 16 + lr) * 64 + ((kh * 4 + lq) ^ swz) * 8];
#pragma unroll
            for (int j = 0; j < 2; j++)
                bfr[kh][j] = *(const bf16x8*)&bs[(wn + j * 16 + lr) * 64 + ((kh * 4 + lq) ^ swz) * 8];
        }
#pragma unroll
        for (int kh = 0; kh < 2; kh++)
#pragma unroll
            for (int ii = 0; ii < 4; ii++)
#pragma unroll
                for (int j = 0; j < 2; j++)
                    acc[ii][j] = __builtin_amdgcn_mfma_f32_16x16x32_bf16(af[kh][ii], bfr[kh][j], acc[ii][j], 0, 0, 0);
    }

#pragma unroll
    for (int ii = 0; ii < 4; ii++) {
        int mg = bm * 128 + wm + ii * 16 + lq * 4;
        int b = mg >> 11, s = mg & 2047;
#pragma unroll
        for (int j = 0; j < 2; j++) {
            int cg = bn * 64 + wn + j * 16 + lr;
            float bv = bias[cg];
            if constexpr (QKV_EPI) {
                int d = cg & 63;
                if (cg < 1024) {
                    int h = cg >> 6;
                    ushort* dst = Qb + ((size_t)(b * NHEADS + h) * SEQ + s) * DK + d;
#pragma unroll
                    for (int r = 0; r < 4; r++)
                        dst[r * DK] = f2bf((acc[ii][j][r] + bv) * SCL_Q);
                } else if (cg < 1280) {
                    int g = (cg - 1024) >> 6;
                    ushort* dst = Kb + ((size_t)(b * NGROUPS + g) * SEQ + s) * DK + d;
#pragma unroll
                    for (int r = 0; r < 4; r++) dst[r * DK] = f2bf(acc[ii][j][r] + bv);
                } else {
                    int g = (cg - 1280) >> 6;
                    // permuted V^T column: 4-key group kg -> position (kg&3)*2+(kg>>2)
                    int s4 = s >> 2, kg = s4 & 7;
                    int col = ((s4 >> 3) << 5) + (((((kg & 3) << 1) | (kg >> 2))) << 2);
                    ushort4 pk;
                    pk.x = f2bf(acc[ii][j][0] + bv); pk.y = f2bf(acc[ii][j][1] + bv);
                    pk.z = f2bf(acc[ii][j][2] + bv); pk.w = f2bf(acc[ii][j][3] + bv);
                    *(ushort4*)(Vtg + ((size_t)(b * NGROUPS + g) * DK + d) * SEQ + col) = pk;
                }
            } else {
#pragma unroll
                for (int r = 0; r < 4; r++)
                    outF[(size_t)(mg + r) * DM + cg] = acc[ii][j][r] + bv;
            }
        }
    }
}

// ---------------------------------------------------------------------------
// Attention: 512 blocks, XCD-local: bg = i&7 (one (b,g) per XCD -> K/V L2
// resident). Block = 128 q-rows of one head; 4 waves split (wq, wt):
// wave handles 64 q x 32 t per 64-key tile -> kf 4 + vf 4 b128 per iter.
// S^T = K·Q^T; P stays in registers as K=32 B-frags vs column-permuted V^T.
// Partial O over t-halves combined once at the end via LDS overlay.
// ---------------------------------------------------------------------------
__global__ __launch_bounds__(256, 2) void gqa_attn_kernel(
        const ushort* __restrict__ Qb, const ushort* __restrict__ Kb,
        const ushort* __restrict__ Vtg, ushort* __restrict__ ctx)
{
    __shared__ ushort smem[2][2][64 * 64];   // [K/V][buf][tile]  (32 KB)
    __shared__ float accX[2][4][16];

    const int tid = threadIdx.x, wave = tid >> 6, lane = tid & 63;
    const int lr = lane & 15, lq = lane >> 4;
    const int swz = lr & 7;
    const int wq = wave & 1, wt = wave >> 1;
    const int i = blockIdx.x;
    const int bg = i & 7, s2 = i >> 3;          // s2: 0..63
    const int qt = s2 & 15, h = s2 >> 4;
    const int b = bg >> 2, g = bg & 3, hg = g * 4 + h;

    const ushort* Qh = Qb  + (size_t)(b * NHEADS  + hg) * SEQ * DK;
    const ushort* Kg = Kb  + (size_t)(b * NGROUPS + g)  * SEQ * DK;
    const ushort* Vg = Vtg + (size_t)(b * NGROUPS + g)  * DK * SEQ;

    const int s0 = qt * 128 + wq * 64;
    const int tb = wt * 32;                      // wave's t-stripe in tile

    bf16x8 qf[4][2];
#pragma unroll
    for (int qs = 0; qs < 4; qs++)
#pragma unroll
        for (int kh = 0; kh < 2; kh++)
            qf[qs][kh] = *(const bf16x8*)(Qh + (size_t)(s0 + qs * 16 + lr) * DK + kh * 32 + lq * 8);

    // staging: slots p=0,1 over 256 threads; row = slot>>3 in 0..63
    const ushort* srcK[2]; const ushort* srcV[2]; int dstOff[2];
#pragma unroll
    for (int p = 0; p < 2; p++) {
        int slt = p * 256 + tid;
        int row = slt >> 3, cb = (slt & 7) ^ (row & 7);
        srcK[p] = Kg + (size_t)row * DK + cb * 8;
        srcV[p] = Vg + (size_t)row * SEQ + cb * 8;
        dstOff[p] = p * 2048 + wave * 512;
    }

    f32x4 of[4][4];
#pragma unroll
    for (int qs = 0; qs < 4; qs++)
#pragma unroll
        for (int j = 0; j < 4; j++) of[qs][j] = (f32x4){0.f, 0.f, 0.f, 0.f};
    f32x4 accL[4];
#pragma unroll
    for (int qs = 0; qs < 4; qs++) accL[qs] = (f32x4){0.f, 0.f, 0.f, 0.f};

    bf16x8 ones;
#pragma unroll
    for (int k = 0; k < 8; k++) ones[k] = (short)0x3F80;   // bf16 1.0

#pragma unroll
    for (int p = 0; p < 2; p++) {
        gll16(srcK[p], &smem[0][0][dstOff[p]]);
        gll16(srcV[p], &smem[1][0][dstOff[p]]);
    }

    for (int it = 0; it < 32; it++) {
        __syncthreads();
        if (it < 31) {
            int buf = (it + 1) & 1, t0 = (it + 1) * 64;
#pragma unroll
            for (int p = 0; p < 2; p++) {
                gll16(srcK[p] + (size_t)t0 * DK, &smem[0][buf][dstOff[p]]);
                gll16(srcV[p] + t0, &smem[1][buf][dstOff[p]]);
            }
        }
        const ushort* ks = smem[0][it & 1];
        const ushort* vs = smem[1][it & 1];

        bf16x8 kf[2][2];
#pragma unroll
        for (int nt = 0; nt < 2; nt++)
#pragma unroll
            for (int kh = 0; kh < 2; kh++)
                kf[nt][kh] = *(const bf16x8*)&ks[((tb + nt * 16 + lr) * 8 + ((kh * 4 + lq) ^ swz)) * 8];

        bf16x8 vf[4];
#pragma unroll
        for (int j = 0; j < 4; j++)
            vf[j] = *(const bf16x8*)&vs[((j * 16 + lr) * 8 + ((wt * 4 + lq) ^ swz)) * 8];

        // S^T[t][q] over the wave's 32-t stripe (Q pre-scaled -> log2 domain)
        f32x4 sc[4][2];
#pragma unroll
        for (int qs = 0; qs < 4; qs++)
#pragma unroll
            for (int nt = 0; nt < 2; nt++) {
                f32x4 s = (f32x4){0.f, 0.f, 0.f, 0.f};
                s = __builtin_amdgcn_mfma_f32_16x16x32_bf16(kf[nt][0], qf[qs][0], s, 0, 0, 0);
                s = __builtin_amdgcn_mfma_f32_16x16x32_bf16(kf[nt][1], qf[qs][1], s, 0, 0, 0);
                sc[qs][nt] = s;
            }

        // exp2 -> truncate-pack to single K=32 B-frag per qs; sums via ones-MFMA
        union PF { bf16x8 v; uint32_t w[4]; };
        PF pf[4];
#pragma unroll
        for (int qs = 0; qs < 4; qs++) {
#pragma unroll
            for (int nt = 0; nt < 2; nt++) {
                union { float f; uint32_t u; } e0, e1, e2, e3;
                e0.f = __builtin_amdgcn_exp2f(sc[qs][nt][0]);
                e1.f = __builtin_amdgcn_exp2f(sc[qs][nt][1]);
                e2.f = __builtin_amdgcn_exp2f(sc[qs][nt][2]);
                e3.f = __builtin_amdgcn_exp2f(sc[qs][nt][3]);
                pf[qs].w[nt * 2 + 0] = __builtin_amdgcn_perm(e1.u, e0.u, 0x07060302u);
                pf[qs].w[nt * 2 + 1] = __builtin_amdgcn_perm(e3.u, e2.u, 0x07060302u);
            }
            accL[qs] = __builtin_amdgcn_mfma_f32_16x16x32_bf16(ones, pf[qs].v, accL[qs], 0, 0, 0);
        }

        // O^T[d][q] += V^T(stripe) · P
#pragma unroll
        for (int qs = 0; qs < 4; qs++)
#pragma unroll
            for (int j = 0; j < 4; j++)
                of[qs][j] = __builtin_amdgcn_mfma_f32_16x16x32_bf16(vf[j], pf[qs].v, of[qs][j], 0, 0, 0);
    }

    // ---- combine t-halves (wt=1 -> LDS overlay -> wt=0 adds) ----
    __syncthreads();                      // all smem reads done; safe to overlay
    float* comb = (float*)&smem[0][0][0]; // 32 KB: [wq][ (qs*4+j)*256 + lane*4 ]
    if (wt == 1) {
        float* cw = comb + wq * 4096;
#pragma unroll
        for (int qs = 0; qs < 4; qs++)
#pragma unroll
            for (int j = 0; j < 4; j++)
                *(f32x4*)&cw[(qs * 4 + j) * 256 + lane * 4] = of[qs][j];
        if (lq == 0) {
#pragma unroll
            for (int qs = 0; qs < 4; qs++) accX[wq][qs][lr] = accL[qs][0];
        }
    }
    __syncthreads();
    if (wt == 0) {
        const float* cw = comb + wq * 4096;
        float inv[4];
#pragma unroll
        for (int qs = 0; qs < 4; qs++)
            inv[qs] = 1.0f / (accL[qs][0] + accX[wq][qs][lr]);
        ushort* cbp = ctx + (size_t)b * SEQ * DM;
#pragma unroll
        for (int qs = 0; qs < 4; qs++) {
            int s = s0 + qs * 16 + lr;
#pragma unroll
            for (int j = 0; j < 4; j++) {
                f32x4 o2 = of[qs][j] + *(const f32x4*)&cw[(qs * 4 + j) * 256 + lane * 4];
                ushort4 o;
                o.x = f2bf(o2[0] * inv[qs]);
                o.y = f2bf(o2[1] * inv[qs]);
                o.z = f2bf(o2[2] * inv[qs]);
                o.w = f2bf(o2[3] * inv[qs]);
                *(ushort4*)(cbp + (size_t)s * DM + hg * 64 + j * 16 + lq * 4) = o;
            }
        }
    }
}

// ---------------------------------------------------------------------------
extern "C" void kernel_launch(void* const* d_in, const int* in_sizes, int n_in,
                              void* d_out, int out_size, void* d_ws, size_t ws_size,
                              hipStream_t stream) {
    const float* x  = (const float*)d_in[0];
    const float* WQ = (const float*)d_in[1];
    const float* bQ = (const float*)d_in[2];
    const float* WK = (const float*)d_in[3];
    const float* bK = (const float*)d_in[4];
    const float* WV = (const float*)d_in[5];
    const float* bV = (const float*)d_in[6];
    const float* WO = (const float*)d_in[7];
    const float* bO = (const float*)d_in[8];

    ushort* Qb    = (ushort*)d_ws;
    ushort* Kb    = Qb + QB_ELEMS;
    ushort* Vtg   = Kb + KB_ELEMS;
    ushort* xc    = Vtg + VT_ELEMS;       // xbf (QKV input), later reused as ctx
    ushort* WqkvT = xc + XC_ELEMS;
    ushort* WoT   = WqkvT + WQKV_ELEMS;
    float*  bcat  = (float*)(WoT + WO_ELEMS);

    gqa_prep_kernel<<<897, 256, 0, stream>>>(x, WQ, WK, WV, WO, bQ, bK, bV,
                                             xc, WqkvT, WoT, bcat);
    gqa_gemm_kernel<true, 24><<<768, 256, 0, stream>>>(
        xc, WqkvT, bcat, nullptr, Qb, Kb, Vtg);
    gqa_attn_kernel<<<512, 256, 0, stream>>>(Qb, Kb, Vtg, xc);
    gqa_gemm_kernel<false, 16><<<512, 256, 0, stream>>>(
        xc, WoT, bO, (float*)d_out, nullptr, nullptr, nullptr);
}

// Round 6
// 160.658 us; speedup vs baseline: 1.0165x; 1.0165x over previous
//
#include <hip/hip_runtime.h>
#include <cstdint>
#include <cstddef>

typedef short bf16x8 __attribute__((ext_vector_type(8)));
typedef float f32x4 __attribute__((ext_vector_type(4)));

#define DM 1024
#define NHEADS 16
#define NGROUPS 4
#define DK 64
#define BATCH 2
#define SEQ 2048
#define MROWS 4096

#define QB_ELEMS   ((size_t)BATCH*NHEADS*SEQ*DK)   // 4M shorts
#define KB_ELEMS   ((size_t)BATCH*NGROUPS*SEQ*DK)  // 1M
#define VT_ELEMS   KB_ELEMS                        // 1M  ([b][g][d][col] permuted)
#define XC_ELEMS   ((size_t)MROWS*DM)              // 4M  (xbf, later reused as ctx)
#define WQKV_ELEMS ((size_t)1536*DM)
#define WO_ELEMS   ((size_t)DM*DM)

#define SCL_Q 0.180336880f    // (1/sqrt(64)) * log2(e), folded into Q

__device__ __forceinline__ ushort f2bf(float f) {          // RNE
    union { float f; uint32_t u; } a; a.f = f;
    uint32_t u = a.u;
    return (ushort)((u + 0x7FFFu + ((u >> 16) & 1u)) >> 16);
}

// async global->LDS, 16B/lane; LDS dest = wave-uniform base + lane*16
__device__ __forceinline__ void gll16(const void* g, void* l) {
    __builtin_amdgcn_global_load_lds((const __attribute__((address_space(1))) void*)g,
                                     (__attribute__((address_space(3))) void*)l, 16, 0, 0);
}

// 64x64 fp32->bf16 transpose tile through LDS (tl must be float[64][65])
__device__ __forceinline__ void transpose_tile(
        const float* __restrict__ src, int src_ld, ushort* __restrict__ dst,
        int r0, int c0, int tid, float (*tl)[65])
{
    const int rr = tid >> 4, cc = (tid & 15) * 4;
#pragma unroll
    for (int p = 0; p < 4; p++) {
        int r = rr + p * 16;
        float4 v = *(const float4*)(src + (size_t)(r0 + r) * src_ld + c0 + cc);
        tl[cc + 0][r] = v.x; tl[cc + 1][r] = v.y;
        tl[cc + 2][r] = v.z; tl[cc + 3][r] = v.w;
    }
    __syncthreads();
#pragma unroll
    for (int p = 0; p < 4; p++) {
        int c = rr + p * 16;
        ushort4 o;
        o.x = f2bf(tl[c][cc + 0]); o.y = f2bf(tl[c][cc + 1]);
        o.z = f2bf(tl[c][cc + 2]); o.w = f2bf(tl[c][cc + 3]);
        *(ushort4*)(dst + (size_t)(c0 + c) * 1024 + r0 + cc) = o;
    }
}

// ---------------------------------------------------------------------------
// Prep (641 blocks): W_Q/W_K/W_V transposes -> WqkvT, x fp32->bf16, bias.
// (W_O transpose rides inside the QKV GEMM launch.)
// ---------------------------------------------------------------------------
__global__ __launch_bounds__(256) void gqa_prep_kernel(
        const float* __restrict__ x,
        const float* __restrict__ WQ, const float* __restrict__ WK,
        const float* __restrict__ WV,
        const float* __restrict__ bQ, const float* __restrict__ bK,
        const float* __restrict__ bV,
        ushort* __restrict__ xbf, ushort* __restrict__ WqkvT,
        float* __restrict__ bcat)
{
    __shared__ float tl[64][65];
    const int bid = blockIdx.x, tid = threadIdx.x;
    if (bid < 256) {            // WQ [d][c] -> WqkvT rows c
        transpose_tile(WQ, 1024, WqkvT, (bid >> 4) * 64, (bid & 15) * 64, tid, tl);
    } else if (bid < 320) {     // WK[g] [d][k] -> rows 1024+g*64
        int t = bid - 256, g = t >> 4;
        transpose_tile(WK + (size_t)g * 1024 * 64, 64,
                       WqkvT + (size_t)(1024 + g * 64) * 1024,
                       (t & 15) * 64, 0, tid, tl);
    } else if (bid < 384) {     // WV[g] -> rows 1280+g*64
        int t = bid - 320, g = t >> 4;
        transpose_tile(WV + (size_t)g * 1024 * 64, 64,
                       WqkvT + (size_t)(1280 + g * 64) * 1024,
                       (t & 15) * 64, 0, tid, tl);
    } else if (bid < 640) {     // x convert
        int cid = bid - 384;
        const float* xs = x + (size_t)cid * 16384;
        ushort* xd = xbf + (size_t)cid * 16384;
#pragma unroll
        for (int p = 0; p < 16; p++) {
            float4 v = *(const float4*)(xs + p * 1024 + tid * 4);
            ushort4 o = { f2bf(v.x), f2bf(v.y), f2bf(v.z), f2bf(v.w) };
            *(ushort4*)(xd + p * 1024 + tid * 4) = o;
        }
    } else {
        for (int i = tid; i < 1536; i += 256) {
            float v = (i < 1024) ? bQ[i] : (i < 1280 ? bK[i - 1024] : bV[i - 1280]);
            bcat[i] = v;
        }
    }
}

// ---------------------------------------------------------------------------
// GEMM: C[4096][N] = A[4096][1024]*B (+bias), BT[N][1024] bf16.
// Tile 64x64, BK=64, 4 waves (2x2, wave 32x32), gll16 dbuf, 1 barrier/iter.
// 32 KB LDS, launch_bounds(256,4) -> 4 blocks/CU resident.
// RIDERS: first 256 blocks transpose W_O -> WoT (independent work, consumed
// by the out-projection GEMM two launches later).
// ---------------------------------------------------------------------------
template<bool QKV_EPI, int BN, bool RIDERS>
__global__ __launch_bounds__(256, 4) void gqa_gemm_kernel(
        const ushort* __restrict__ A, const ushort* __restrict__ BT,
        const float* __restrict__ bias, float* __restrict__ outF,
        ushort* __restrict__ Qb, ushort* __restrict__ Kb, ushort* __restrict__ Vtg,
        const float* __restrict__ WO, ushort* __restrict__ WoT)
{
    __shared__ ushort smem[4][4096];     // As buf0/1, Bs buf0/1 (32 KB)
    const int tid = threadIdx.x;
    int i = blockIdx.x;

    if constexpr (RIDERS) {
        if (i < 256) {   // W_O transpose rider
            float (*tl)[65] = (float(*)[65])&smem[0][0];
            transpose_tile(WO, 1024, WoT, (i >> 4) * 64, (i & 15) * 64, tid, tl);
            return;
        }
        i -= 256;
    }

    const int xcd = i & 7, slot = i >> 3;
    const int bm = (slot / BN) * 8 + xcd;
    const int bn = slot % BN;
    const int wave = tid >> 6, lane = tid & 63;
    const int wm = (wave & 1) * 32, wn = (wave >> 1) * 32;
    const int lr = lane & 15, lq = lane >> 4;
    const int swz = lr & 7;

    // staging: 2 slots each for A (64x64) and B (64x64); chunk XOR swizzle
    const ushort* srcA[2]; const ushort* srcB[2]; int dstOff[2];
#pragma unroll
    for (int p = 0; p < 2; p++) {
        int slt = p * 256 + tid;
        int row = slt >> 3, cb = (slt & 7) ^ (row & 7);
        srcA[p] = A  + (size_t)(bm * 64 + row) * 1024 + cb * 8;
        srcB[p] = BT + (size_t)(bn * 64 + row) * 1024 + cb * 8;
        dstOff[p] = p * 2048 + wave * 512;
    }

    f32x4 acc[2][2];
#pragma unroll
    for (int ii = 0; ii < 2; ii++)
#pragma unroll
        for (int j = 0; j < 2; j++) acc[ii][j] = (f32x4){0.f, 0.f, 0.f, 0.f};

#pragma unroll
    for (int p = 0; p < 2; p++) {
        gll16(srcA[p], &smem[0][dstOff[p]]);
        gll16(srcB[p], &smem[2][dstOff[p]]);
    }

    for (int kt = 0; kt < 16; kt++) {
        __syncthreads();
        if (kt < 15) {
            int buf = (kt + 1) & 1, ko = (kt + 1) * 64;
#pragma unroll
            for (int p = 0; p < 2; p++) {
                gll16(srcA[p] + ko, &smem[buf][dstOff[p]]);
                gll16(srcB[p] + ko, &smem[2 + buf][dstOff[p]]);
            }
        }
        const ushort* as = smem[kt & 1];
        const ushort* bs = smem[2 + (kt & 1)];
        bf16x8 af[2][2], bfr[2][2];
#pragma unroll
        for (int kh = 0; kh < 2; kh++) {
#pragma unroll
            for (int ii = 0; ii < 2; ii++)
                af[kh][ii] = *(const bf16x8*)&as[(wm + ii * 16 + lr) * 64 + ((kh * 4 + lq) ^ swz) * 8];
#pragma unroll
            for (int j = 0; j < 2; j++)
                bfr[kh][j] = *(const bf16x8*)&bs[(wn + j * 16 + lr) * 64 + ((kh * 4 + lq) ^ swz) * 8];
        }
#pragma unroll
        for (int kh = 0; kh < 2; kh++)
#pragma unroll
            for (int ii = 0; ii < 2; ii++)
#pragma unroll
                for (int j = 0; j < 2; j++)
                    acc[ii][j] = __builtin_amdgcn_mfma_f32_16x16x32_bf16(af[kh][ii], bfr[kh][j], acc[ii][j], 0, 0, 0);
    }

#pragma unroll
    for (int ii = 0; ii < 2; ii++) {
        int mg = bm * 64 + wm + ii * 16 + lq * 4;
        int b = mg >> 11, s = mg & 2047;
#pragma unroll
        for (int j = 0; j < 2; j++) {
            int cg = bn * 64 + wn + j * 16 + lr;
            float bv = bias[cg];
            if constexpr (QKV_EPI) {
                int d = cg & 63;
                if (cg < 1024) {
                    int h = cg >> 6;
                    ushort* dst = Qb + ((size_t)(b * NHEADS + h) * SEQ + s) * DK + d;
#pragma unroll
                    for (int r = 0; r < 4; r++)
                        dst[r * DK] = f2bf((acc[ii][j][r] + bv) * SCL_Q);
                } else if (cg < 1280) {
                    int g = (cg - 1024) >> 6;
                    ushort* dst = Kb + ((size_t)(b * NGROUPS + g) * SEQ + s) * DK + d;
#pragma unroll
                    for (int r = 0; r < 4; r++) dst[r * DK] = f2bf(acc[ii][j][r] + bv);
                } else {
                    int g = (cg - 1280) >> 6;
                    // permuted V^T column: 4-key group kg -> position (kg&3)*2+(kg>>2)
                    int s4 = s >> 2, kg = s4 & 7;
                    int col = ((s4 >> 3) << 5) + (((((kg & 3) << 1) | (kg >> 2))) << 2);
                    ushort4 pk;
                    pk.x = f2bf(acc[ii][j][0] + bv); pk.y = f2bf(acc[ii][j][1] + bv);
                    pk.z = f2bf(acc[ii][j][2] + bv); pk.w = f2bf(acc[ii][j][3] + bv);
                    *(ushort4*)(Vtg + ((size_t)(b * NGROUPS + g) * DK + d) * SEQ + col) = pk;
                }
            } else {
#pragma unroll
                for (int r = 0; r < 4; r++)
                    outF[(size_t)(mg + r) * DM + cg] = acc[ii][j][r] + bv;
            }
        }
    }
}

// ---------------------------------------------------------------------------
// Attention (unchanged control from R5): 512 blocks, 4 waves split (wq, wt):
// wave = 64 q x 32 t per 64-key tile. S^T = K·Q^T; P stays in registers as
// K=32 B-frags vs column-permuted V^T; t-halves combined via LDS overlay.
// ---------------------------------------------------------------------------
__global__ __launch_bounds__(256, 2) void gqa_attn_kernel(
        const ushort* __restrict__ Qb, const ushort* __restrict__ Kb,
        const ushort* __restrict__ Vtg, ushort* __restrict__ ctx)
{
    __shared__ ushort smem[2][2][64 * 64];   // [K/V][buf][tile]  (32 KB)
    __shared__ float accX[2][4][16];

    const int tid = threadIdx.x, wave = tid >> 6, lane = tid & 63;
    const int lr = lane & 15, lq = lane >> 4;
    const int swz = lr & 7;
    const int wq = wave & 1, wt = wave >> 1;
    const int i = blockIdx.x;
    const int bg = i & 7, s2 = i >> 3;
    const int qt = s2 & 15, h = s2 >> 4;
    const int b = bg >> 2, g = bg & 3, hg = g * 4 + h;

    const ushort* Qh = Qb  + (size_t)(b * NHEADS  + hg) * SEQ * DK;
    const ushort* Kg = Kb  + (size_t)(b * NGROUPS + g)  * SEQ * DK;
    const ushort* Vg = Vtg + (size_t)(b * NGROUPS + g)  * DK * SEQ;

    const int s0 = qt * 128 + wq * 64;
    const int tb = wt * 32;

    bf16x8 qf[4][2];
#pragma unroll
    for (int qs = 0; qs < 4; qs++)
#pragma unroll
        for (int kh = 0; kh < 2; kh++)
            qf[qs][kh] = *(const bf16x8*)(Qh + (size_t)(s0 + qs * 16 + lr) * DK + kh * 32 + lq * 8);

    const ushort* srcK[2]; const ushort* srcV[2]; int dstOff[2];
#pragma unroll
    for (int p = 0; p < 2; p++) {
        int slt = p * 256 + tid;
        int row = slt >> 3, cb = (slt & 7) ^ (row & 7);
        srcK[p] = Kg + (size_t)row * DK + cb * 8;
        srcV[p] = Vg + (size_t)row * SEQ + cb * 8;
        dstOff[p] = p * 2048 + wave * 512;
    }

    f32x4 of[4][4];
#pragma unroll
    for (int qs = 0; qs < 4; qs++)
#pragma unroll
        for (int j = 0; j < 4; j++) of[qs][j] = (f32x4){0.f, 0.f, 0.f, 0.f};
    f32x4 accL[4];
#pragma unroll
    for (int qs = 0; qs < 4; qs++) accL[qs] = (f32x4){0.f, 0.f, 0.f, 0.f};

    bf16x8 ones;
#pragma unroll
    for (int k = 0; k < 8; k++) ones[k] = (short)0x3F80;

#pragma unroll
    for (int p = 0; p < 2; p++) {
        gll16(srcK[p], &smem[0][0][dstOff[p]]);
        gll16(srcV[p], &smem[1][0][dstOff[p]]);
    }

    for (int it = 0; it < 32; it++) {
        __syncthreads();
        if (it < 31) {
            int buf = (it + 1) & 1, t0 = (it + 1) * 64;
#pragma unroll
            for (int p = 0; p < 2; p++) {
                gll16(srcK[p] + (size_t)t0 * DK, &smem[0][buf][dstOff[p]]);
                gll16(srcV[p] + t0, &smem[1][buf][dstOff[p]]);
            }
        }
        const ushort* ks = smem[0][it & 1];
        const ushort* vs = smem[1][it & 1];

        bf16x8 kf[2][2];
#pragma unroll
        for (int nt = 0; nt < 2; nt++)
#pragma unroll
            for (int kh = 0; kh < 2; kh++)
                kf[nt][kh] = *(const bf16x8*)&ks[((tb + nt * 16 + lr) * 8 + ((kh * 4 + lq) ^ swz)) * 8];

        bf16x8 vf[4];
#pragma unroll
        for (int j = 0; j < 4; j++)
            vf[j] = *(const bf16x8*)&vs[((j * 16 + lr) * 8 + ((wt * 4 + lq) ^ swz)) * 8];

        f32x4 sc[4][2];
#pragma unroll
        for (int qs = 0; qs < 4; qs++)
#pragma unroll
            for (int nt = 0; nt < 2; nt++) {
                f32x4 s = (f32x4){0.f, 0.f, 0.f, 0.f};
                s = __builtin_amdgcn_mfma_f32_16x16x32_bf16(kf[nt][0], qf[qs][0], s, 0, 0, 0);
                s = __builtin_amdgcn_mfma_f32_16x16x32_bf16(kf[nt][1], qf[qs][1], s, 0, 0, 0);
                sc[qs][nt] = s;
            }

        union PF { bf16x8 v; uint32_t w[4]; };
        PF pf[4];
#pragma unroll
        for (int qs = 0; qs < 4; qs++) {
#pragma unroll
            for (int nt = 0; nt < 2; nt++) {
                union { float f; uint32_t u; } e0, e1, e2, e3;
                e0.f = __builtin_amdgcn_exp2f(sc[qs][nt][0]);
                e1.f = __builtin_amdgcn_exp2f(sc[qs][nt][1]);
                e2.f = __builtin_amdgcn_exp2f(sc[qs][nt][2]);
                e3.f = __builtin_amdgcn_exp2f(sc[qs][nt][3]);
                pf[qs].w[nt * 2 + 0] = __builtin_amdgcn_perm(e1.u, e0.u, 0x07060302u);
                pf[qs].w[nt * 2 + 1] = __builtin_amdgcn_perm(e3.u, e2.u, 0x07060302u);
            }
            accL[qs] = __builtin_amdgcn_mfma_f32_16x16x32_bf16(ones, pf[qs].v, accL[qs], 0, 0, 0);
        }

#pragma unroll
        for (int qs = 0; qs < 4; qs++)
#pragma unroll
            for (int j = 0; j < 4; j++)
                of[qs][j] = __builtin_amdgcn_mfma_f32_16x16x32_bf16(vf[j], pf[qs].v, of[qs][j], 0, 0, 0);
    }

    __syncthreads();
    float* comb = (float*)&smem[0][0][0];
    if (wt == 1) {
        float* cw = comb + wq * 4096;
#pragma unroll
        for (int qs = 0; qs < 4; qs++)
#pragma unroll
            for (int j = 0; j < 4; j++)
                *(f32x4*)&cw[(qs * 4 + j) * 256 + lane * 4] = of[qs][j];
        if (lq == 0) {
#pragma unroll
            for (int qs = 0; qs < 4; qs++) accX[wq][qs][lr] = accL[qs][0];
        }
    }
    __syncthreads();
    if (wt == 0) {
        const float* cw = comb + wq * 4096;
        float inv[4];
#pragma unroll
        for (int qs = 0; qs < 4; qs++)
            inv[qs] = 1.0f / (accL[qs][0] + accX[wq][qs][lr]);
        ushort* cbp = ctx + (size_t)b * SEQ * DM;
#pragma unroll
        for (int qs = 0; qs < 4; qs++) {
            int s = s0 + qs * 16 + lr;
#pragma unroll
            for (int j = 0; j < 4; j++) {
                f32x4 o2 = of[qs][j] + *(const f32x4*)&cw[(qs * 4 + j) * 256 + lane * 4];
                ushort4 o;
                o.x = f2bf(o2[0] * inv[qs]);
                o.y = f2bf(o2[1] * inv[qs]);
                o.z = f2bf(o2[2] * inv[qs]);
                o.w = f2bf(o2[3] * inv[qs]);
                *(ushort4*)(cbp + (size_t)s * DM + hg * 64 + j * 16 + lq * 4) = o;
            }
        }
    }
}

// ---------------------------------------------------------------------------
extern "C" void kernel_launch(void* const* d_in, const int* in_sizes, int n_in,
                              void* d_out, int out_size, void* d_ws, size_t ws_size,
                              hipStream_t stream) {
    const float* x  = (const float*)d_in[0];
    const float* WQ = (const float*)d_in[1];
    const float* bQ = (const float*)d_in[2];
    const float* WK = (const float*)d_in[3];
    const float* bK = (const float*)d_in[4];
    const float* WV = (const float*)d_in[5];
    const float* bV = (const float*)d_in[6];
    const float* WO = (const float*)d_in[7];
    const float* bO = (const float*)d_in[8];

    ushort* Qb    = (ushort*)d_ws;
    ushort* Kb    = Qb + QB_ELEMS;
    ushort* Vtg   = Kb + KB_ELEMS;
    ushort* xc    = Vtg + VT_ELEMS;       // xbf (QKV input), later reused as ctx
    ushort* WqkvT = xc + XC_ELEMS;
    ushort* WoT   = WqkvT + WQKV_ELEMS;
    float*  bcat  = (float*)(WoT + WO_ELEMS);

    gqa_prep_kernel<<<641, 256, 0, stream>>>(x, WQ, WK, WV, bQ, bK, bV,
                                             xc, WqkvT, bcat);
    gqa_gemm_kernel<true, 24, true><<<1792, 256, 0, stream>>>(
        xc, WqkvT, bcat, nullptr, Qb, Kb, Vtg, WO, WoT);
    gqa_attn_kernel<<<512, 256, 0, stream>>>(Qb, Kb, Vtg, xc);
    gqa_gemm_kernel<false, 16, false><<<1024, 256, 0, stream>>>(
        xc, WoT, bO, (float*)d_out, nullptr, nullptr, nullptr, nullptr, nullptr);
}